// Round 6
// baseline (1563.662 us; speedup 1.0000x reference)
//
#include <hip/hip_runtime.h>

// LiquidNN LTC: B=512, S=512, D=H=128, O=1, UNFOLDS=6, dt=0.1, tau=1.
// ROUND 6: clean K-split. Block=256 per batch row (grid=512, 2 blocks/CU,
// 8 waves/CU = 2 waves/SIMD for TLP). Thread t: output o=t>>1, K-half kh=t&1.
// Weight footprint per thread = 64 VGPRs (32+32 v2h) -- the only shape the
// allocator has cooperated with (round 0: VGPR=72). Full-K v8h designs
// (rounds 2-5) lost the residency fight every time (VGPR 84/100/132 vs 220
// needed) and were stuck at ~1000 cyc/phase.
// vs round 0 (1513us):
//  - input-map FUSED into unfold 0 (7 phases -> 6); xin kept lane-partial,
//    one shfl_xor per phase on (xp+hp) which pair-sums to full xin+hdot.
//  - no float4 local array + reinterpret alias on the LDS-read path (scratch
//    hazard / suspected VALU inflation): named float4 + __builtin_bit_cast.
//  - amdgpu_waves_per_eu(2,2): pressure target == real occupancy (VGPR cap
//    256 >> ~130 needed) so remat-sinking weight loads has nothing to gain.
//  - single-VGPR in-loop pins on the v2h weights (no tuple-copy churn).

typedef _Float16 v2h __attribute__((ext_vector_type(2)));
typedef _Float16 v8h __attribute__((ext_vector_type(8)));

#define S_LEN 512
#define HDIM  128
#define NUNF  6
#define DTC   0.1f

__device__ __forceinline__ float fast_tanh(float y) {
    // tanh(y) = 1 - 2/(e^{2y}+1); v_exp/v_rcp based, NaN-free at +-inf
    float u = __expf(2.0f * y);
    return 1.0f - __fdividef(2.0f, u + 1.0f);
}

// In-loop pin: loop-carried VGPR dep on a SINGLE register, zero instructions.
#define PIN(V) asm volatile("" : "+v"(V))

// 32 dot2 (64 MACs): weight v2h W[0..31] (static idx) vs 8 named float4 read
// from LDS at BASE (broadcast: <=2 distinct addresses across the wave).
// Accumulates into caller's a0..a3.
#define MATVEC32(W, BASE) do {                                        \
    const float4* _p = reinterpret_cast<const float4*>(BASE);         \
    float4 f0=_p[0], f1=_p[1], f2=_p[2], f3=_p[3];                    \
    float4 f4=_p[4], f5=_p[5], f6=_p[6], f7=_p[7];                    \
    v8h q0=__builtin_bit_cast(v8h,f0), q1=__builtin_bit_cast(v8h,f1); \
    v8h q2=__builtin_bit_cast(v8h,f2), q3=__builtin_bit_cast(v8h,f3); \
    v8h q4=__builtin_bit_cast(v8h,f4), q5=__builtin_bit_cast(v8h,f5); \
    v8h q6=__builtin_bit_cast(v8h,f6), q7=__builtin_bit_cast(v8h,f7); \
    a0=__builtin_amdgcn_fdot2(W[0], q0.s01,a0,false);                 \
    a1=__builtin_amdgcn_fdot2(W[1], q0.s23,a1,false);                 \
    a2=__builtin_amdgcn_fdot2(W[2], q0.s45,a2,false);                 \
    a3=__builtin_amdgcn_fdot2(W[3], q0.s67,a3,false);                 \
    a0=__builtin_amdgcn_fdot2(W[4], q1.s01,a0,false);                 \
    a1=__builtin_amdgcn_fdot2(W[5], q1.s23,a1,false);                 \
    a2=__builtin_amdgcn_fdot2(W[6], q1.s45,a2,false);                 \
    a3=__builtin_amdgcn_fdot2(W[7], q1.s67,a3,false);                 \
    a0=__builtin_amdgcn_fdot2(W[8], q2.s01,a0,false);                 \
    a1=__builtin_amdgcn_fdot2(W[9], q2.s23,a1,false);                 \
    a2=__builtin_amdgcn_fdot2(W[10],q2.s45,a2,false);                 \
    a3=__builtin_amdgcn_fdot2(W[11],q2.s67,a3,false);                 \
    a0=__builtin_amdgcn_fdot2(W[12],q3.s01,a0,false);                 \
    a1=__builtin_amdgcn_fdot2(W[13],q3.s23,a1,false);                 \
    a2=__builtin_amdgcn_fdot2(W[14],q3.s45,a2,false);                 \
    a3=__builtin_amdgcn_fdot2(W[15],q3.s67,a3,false);                 \
    a0=__builtin_amdgcn_fdot2(W[16],q4.s01,a0,false);                 \
    a1=__builtin_amdgcn_fdot2(W[17],q4.s23,a1,false);                 \
    a2=__builtin_amdgcn_fdot2(W[18],q4.s45,a2,false);                 \
    a3=__builtin_amdgcn_fdot2(W[19],q4.s67,a3,false);                 \
    a0=__builtin_amdgcn_fdot2(W[20],q5.s01,a0,false);                 \
    a1=__builtin_amdgcn_fdot2(W[21],q5.s23,a1,false);                 \
    a2=__builtin_amdgcn_fdot2(W[22],q5.s45,a2,false);                 \
    a3=__builtin_amdgcn_fdot2(W[23],q5.s67,a3,false);                 \
    a0=__builtin_amdgcn_fdot2(W[24],q6.s01,a0,false);                 \
    a1=__builtin_amdgcn_fdot2(W[25],q6.s23,a1,false);                 \
    a2=__builtin_amdgcn_fdot2(W[26],q6.s45,a2,false);                 \
    a3=__builtin_amdgcn_fdot2(W[27],q6.s67,a3,false);                 \
    a0=__builtin_amdgcn_fdot2(W[28],q7.s01,a0,false);                 \
    a1=__builtin_amdgcn_fdot2(W[29],q7.s23,a1,false);                 \
    a2=__builtin_amdgcn_fdot2(W[30],q7.s45,a2,false);                 \
    a3=__builtin_amdgcn_fdot2(W[31],q7.s67,a3,false);                 \
} while (0)

__global__ __launch_bounds__(256)
__attribute__((amdgpu_waves_per_eu(2, 2)))
void ltc_kernel(const float* __restrict__ x,
                const float* __restrict__ W_in,
                const float* __restrict__ b_in,
                const float* __restrict__ W_r,
                const float* __restrict__ b_r,
                const float* __restrict__ W_fc,
                const float* __restrict__ b_fc,
                float* __restrict__ out)
{
    const int b     = blockIdx.x;
    const int tid   = threadIdx.x;   // 0..255
    const int o     = tid >> 1;      // 0..127
    const int kbase = (tid & 1) * 64;

    __shared__ __align__(16) _Float16 hbuf[2][HDIM];
    __shared__ __align__(16) _Float16 xbuf[2][HDIM];
    __shared__ float red[4];

    // ---- one-time: weight row-halves -> 32+32 v2h (64 VGPRs) ----
    v2h wr[32], wi[32];
    {
        const float4* wrp = reinterpret_cast<const float4*>(W_r  + (size_t)o * HDIM + kbase);
        const float4* wip = reinterpret_cast<const float4*>(W_in + (size_t)o * HDIM + kbase);
#pragma unroll
        for (int j = 0; j < 16; ++j) {
            float4 f = wrp[j];
            wr[2*j]   = v2h{(_Float16)f.x, (_Float16)f.y};
            wr[2*j+1] = v2h{(_Float16)f.z, (_Float16)f.w};
            float4 g = wip[j];
            wi[2*j]   = v2h{(_Float16)g.x, (_Float16)g.y};
            wi[2*j+1] = v2h{(_Float16)g.z, (_Float16)g.w};
        }
    }
    const float binv = b_in[o];
    const float brv  = b_r[o];

    const float* x_row = x + (size_t)b * S_LEN * HDIM;

    // ---- prologue: h = 0, stage x[0] as f16 ----
    if (tid < HDIM) {
        xbuf[0][tid] = (_Float16)x_row[tid];
        hbuf[0][tid] = (_Float16)0.0f;
    }
    __syncthreads();

    float h_o = 0.0f;   // fp32 authoritative h (identical on lane pair)

#pragma unroll 1
    for (int s = 0; s < S_LEN; ++s) {
        // in-loop pins: single-VGPR loop-carried deps, zero instructions
#pragma unroll
        for (int j = 0; j < 32; ++j) { PIN(wr[j]); PIN(wi[j]); }

        // prefetch next step's x (coalesced 4B/lane; staged at u==3)
        float xn = 0.0f;
        if (tid < HDIM && s + 1 < S_LEN)
            xn = x_row[(size_t)(s + 1) * HDIM + tid];

        // ---- phase 0: input-map FUSED with unfold 0 ----
        float xp;   // lane-partial xin (kept for unfolds 1..5)
        {
            float a0=0.f, a1=0.f, a2=0.f, a3=0.f;
            MATVEC32(wi, &xbuf[s & 1][kbase]);
            xp = (a0 + a1) + (a2 + a3);
            a0=0.f; a1=0.f; a2=0.f; a3=0.f;
            MATVEC32(wr, &hbuf[0][kbase]);
            float hp = (a0 + a1) + (a2 + a3);
            float t  = xp + hp;
            t += __shfl_xor(t, 1);            // full xin + hdot on both lanes
            float v = fast_tanh(t + binv + brv);
            h_o += DTC * (v - h_o);
            if ((tid & 1) == 0) hbuf[1][o] = (_Float16)h_o;
            __syncthreads();
        }

        // ---- unfolds 1..5 ----
#pragma unroll
        for (int u = 1; u < NUNF; ++u) {
            float a0=0.f, a1=0.f, a2=0.f, a3=0.f;
            MATVEC32(wr, &hbuf[u & 1][kbase]);
            float hp = (a0 + a1) + (a2 + a3);
            float t  = xp + hp;
            t += __shfl_xor(t, 1);            // full xin + hdot
            float v = fast_tanh(t + binv + brv);
            h_o += DTC * (v - h_o);
            if ((tid & 1) == 0) hbuf[(u + 1) & 1][o] = (_Float16)h_o;
            if (u == 3 && tid < HDIM && s + 1 < S_LEN)
                xbuf[(s + 1) & 1][tid] = (_Float16)xn;
            __syncthreads();
        }
    }

    // ---- epilogue: out[b] = h . W_fc[0,:] + b_fc ----
    float partial = 0.0f;
    if ((tid & 1) == 0) partial = h_o * W_fc[o];
#pragma unroll
    for (int d = 1; d < 64; d <<= 1) partial += __shfl_xor(partial, d);
    if ((tid & 63) == 0) red[tid >> 6] = partial;
    __syncthreads();
    if (tid == 0) out[b] = red[0] + red[1] + red[2] + red[3] + b_fc[0];
}

extern "C" void kernel_launch(void* const* d_in, const int* in_sizes, int n_in,
                              void* d_out, int out_size, void* d_ws, size_t ws_size,
                              hipStream_t stream) {
    const float* x    = (const float*)d_in[0];
    const float* W_in = (const float*)d_in[1];
    const float* b_in = (const float*)d_in[2];
    const float* W_r  = (const float*)d_in[3];
    const float* b_r  = (const float*)d_in[4];
    const float* W_fc = (const float*)d_in[5];
    const float* b_fc = (const float*)d_in[6];
    float* outp = (float*)d_out;
    (void)in_sizes; (void)n_in; (void)out_size; (void)d_ws; (void)ws_size;
    ltc_kernel<<<dim3(512), dim3(256), 0, stream>>>(x, W_in, b_in, W_r, b_r, W_fc, b_fc, outp);
}